// Round 6
// baseline (3191.054 us; speedup 1.0000x reference)
//
#include <hip/hip_runtime.h>
#include <math.h>

#define D    128
#define NH   8
#define RBFD 16
#define SBFD 112
#define LAYERS 3

typedef __attribute__((ext_vector_type(8))) short bf16x8;
typedef __attribute__((ext_vector_type(4))) float f32x4;

__device__ __forceinline__ float siluf(float x){ return x / (1.0f + __expf(-x)); }

__device__ __forceinline__ short f2bf(float f){
  union { float f; unsigned u; } v; v.f = f;
  unsigned r = v.u + 0x7FFFu + ((v.u >> 16) & 1u);   // RNE
  return (short)(r >> 16);
}
__device__ __forceinline__ float bflo(unsigned u){ return __uint_as_float(u << 16); }
__device__ __forceinline__ float bfhi(unsigned u){ return __uint_as_float(u & 0xFFFF0000u); }

// ---------- MFMA GEMM: Y[M,128] = epilogue(X[gather?][.,DIN] @ W[DIN,128]) ----------
template<int DIN, int ACT, bool GATHER, bool HASB, bool HASRES, bool PERM, bool OUTBF, bool INBF>
__global__ __launch_bounds__(256, 2) void k_gemm(
    const void* __restrict__ Xv, const int* __restrict__ gidx,
    const float* __restrict__ W, const float* __restrict__ bias,
    const float* res, void* __restrict__ Yv, const int* __restrict__ operm, int M)
{
  __shared__ short Wt[128 * 128];          // transposed bf16 weights: Wt[col][k]
  if (DIN < 128){
    for (int i = threadIdx.x; i < 128 * 128; i += 256) Wt[i] = 0;
    __syncthreads();
  }
  for (int i = threadIdx.x; i < DIN * 128; i += 256){
    int k = i >> 7, c = i & 127;
    Wt[c * 128 + k] = f2bf(W[i]);
  }
  __syncthreads();

  const int lane = threadIdx.x & 63;
  const int wave = threadIdx.x >> 6;
  const int col0 = lane & 15;
  const int kg   = lane >> 4;

  bf16x8 Bf[8][4];
  #pragma unroll
  for (int ct = 0; ct < 8; ct++)
    #pragma unroll
    for (int s = 0; s < 4; s++)
      Bf[ct][s] = *(const bf16x8*)&Wt[(ct * 16 + col0) * 128 + s * 32 + kg * 8];

  float bs[8];
  if (HASB){
    #pragma unroll
    for (int ct = 0; ct < 8; ct++) bs[ct] = bias[ct * 16 + col0];
  }

  const float* __restrict__ Xf = (const float*)Xv;
  const unsigned short* __restrict__ Xb = (const unsigned short*)Xv;
  float* __restrict__ Yf = (float*)Yv;
  unsigned short* __restrict__ Yb = (unsigned short*)Yv;

  const long tiles = ((long)M + 63) >> 6;
  for (long t = blockIdx.x; t < tiles; t += gridDim.x){
    const long rbase = t * 64 + wave * 16;
    const long arow  = rbase + col0;
    long srow = 0;
    if (arow < M) srow = GATHER ? (long)gidx[arow] : arow;

    bf16x8 Af[4];
    #pragma unroll
    for (int s = 0; s < 4; s++){
      const int kb = s * 32 + kg * 8;
      bf16x8 a;
      if (DIN == 128 || kb + 8 <= DIN){
        if (INBF){
          a = *(const bf16x8*)(Xb + srow * DIN + kb);
        } else {
          const float* Xp = Xf + srow * DIN;
          float4 lo = *(const float4*)(Xp + kb);
          float4 hi = *(const float4*)(Xp + kb + 4);
          a[0]=f2bf(lo.x); a[1]=f2bf(lo.y); a[2]=f2bf(lo.z); a[3]=f2bf(lo.w);
          a[4]=f2bf(hi.x); a[5]=f2bf(hi.y); a[6]=f2bf(hi.z); a[7]=f2bf(hi.w);
        }
      } else {
        #pragma unroll
        for (int j = 0; j < 8; j++) a[j] = 0;
      }
      Af[s] = a;
    }

    f32x4 acc[8];
    #pragma unroll
    for (int ct = 0; ct < 8; ct++){ acc[ct][0]=0.f; acc[ct][1]=0.f; acc[ct][2]=0.f; acc[ct][3]=0.f; }
    #pragma unroll
    for (int ct = 0; ct < 8; ct++)
      #pragma unroll
      for (int s = 0; s < 4; s++)
        acc[ct] = __builtin_amdgcn_mfma_f32_16x16x32_bf16(Af[s], Bf[ct][s], acc[ct], 0, 0, 0);

    #pragma unroll
    for (int r = 0; r < 4; r++){
      const long orow = rbase + kg * 4 + r;
      if (orow >= M) continue;
      const long wrow = PERM ? (long)operm[orow] : orow;
      #pragma unroll
      for (int ct = 0; ct < 8; ct++){
        const int c = ct * 16 + col0;
        float v = acc[ct][r];
        if (HASB) v += bs[ct];
        if (ACT)  v = siluf(v);
        if (HASRES) v += res[orow * D + c];
        if (OUTBF) Yb[wrow * D + c] = (unsigned short)f2bf(v);
        else       Yf[wrow * D + c] = v;
      }
    }
  }
}

// ---------- fused edgenn: ek = silu(X[gidx]@W1+b1) @ W2 + b2 -> bf16, permuted ----------
__global__ __launch_bounds__(256, 2) void k_gemm2(
    const float* __restrict__ X, const int* __restrict__ gidx,
    const float* __restrict__ W1, const float* __restrict__ b1,
    const float* __restrict__ W2, const float* __restrict__ b2,
    unsigned short* __restrict__ Y, const int* __restrict__ operm, int M)
{
  __shared__ short W1t[128 * 128];
  __shared__ short W2t[128 * 128];
  __shared__ short Ts[64 * 128];
  for (int i = threadIdx.x; i < 128 * 128; i += 256){
    int k = i >> 7, c = i & 127;
    W1t[c * 128 + k] = f2bf(W1[i]);
    W2t[c * 128 + k] = f2bf(W2[i]);
  }
  __syncthreads();

  const int lane = threadIdx.x & 63;
  const int wave = threadIdx.x >> 6;
  const int col0 = lane & 15;
  const int kg   = lane >> 4;

  bf16x8 B1f[8][4];
  #pragma unroll
  for (int ct = 0; ct < 8; ct++)
    #pragma unroll
    for (int s = 0; s < 4; s++)
      B1f[ct][s] = *(const bf16x8*)&W1t[(ct * 16 + col0) * 128 + s * 32 + kg * 8];

  float bs1[8], bs2[8];
  #pragma unroll
  for (int ct = 0; ct < 8; ct++){ bs1[ct] = b1[ct * 16 + col0]; bs2[ct] = b2[ct * 16 + col0]; }

  const long tiles = ((long)M + 63) >> 6;
  for (long t = blockIdx.x; t < tiles; t += gridDim.x){
    const long rbase = t * 64 + wave * 16;
    const long arow  = rbase + col0;
    long srow = 0;
    if (arow < M) srow = (long)gidx[arow];
    const float* Xp = X + srow * D;

    bf16x8 Af[4];
    #pragma unroll
    for (int s = 0; s < 4; s++){
      const int kb = s * 32 + kg * 8;
      float4 lo = *(const float4*)(Xp + kb);
      float4 hi = *(const float4*)(Xp + kb + 4);
      bf16x8 a;
      a[0]=f2bf(lo.x); a[1]=f2bf(lo.y); a[2]=f2bf(lo.z); a[3]=f2bf(lo.w);
      a[4]=f2bf(hi.x); a[5]=f2bf(hi.y); a[6]=f2bf(hi.z); a[7]=f2bf(hi.w);
      Af[s] = a;
    }

    f32x4 acc[8];
    #pragma unroll
    for (int ct = 0; ct < 8; ct++){ acc[ct][0]=0.f; acc[ct][1]=0.f; acc[ct][2]=0.f; acc[ct][3]=0.f; }
    #pragma unroll
    for (int ct = 0; ct < 8; ct++)
      #pragma unroll
      for (int s = 0; s < 4; s++)
        acc[ct] = __builtin_amdgcn_mfma_f32_16x16x32_bf16(Af[s], B1f[ct][s], acc[ct], 0, 0, 0);

    #pragma unroll
    for (int ct = 0; ct < 8; ct++){
      const int c = ct * 16 + col0;
      #pragma unroll
      for (int r = 0; r < 4; r++){
        const int row = wave * 16 + kg * 4 + r;
        const int gg = (c >> 3) ^ (row & 7);
        Ts[row * 128 + gg * 8 + (c & 7)] = f2bf(siluf(acc[ct][r] + bs1[ct]));
      }
    }
    __syncthreads();

    const int row2 = wave * 16 + col0;
    bf16x8 A2f[4];
    #pragma unroll
    for (int s = 0; s < 4; s++){
      const int chunk = (s * 4 + kg) ^ (row2 & 7);
      A2f[s] = *(const bf16x8*)&Ts[row2 * 128 + chunk * 8];
    }
    __syncthreads();

    #pragma unroll
    for (int ct = 0; ct < 8; ct++){ acc[ct][0]=0.f; acc[ct][1]=0.f; acc[ct][2]=0.f; acc[ct][3]=0.f; }
    #pragma unroll
    for (int ct = 0; ct < 8; ct++){
      bf16x8 B2v[4];
      #pragma unroll
      for (int s = 0; s < 4; s++)
        B2v[s] = *(const bf16x8*)&W2t[(ct * 16 + col0) * 128 + s * 32 + kg * 8];
      #pragma unroll
      for (int s = 0; s < 4; s++)
        acc[ct] = __builtin_amdgcn_mfma_f32_16x16x32_bf16(A2f[s], B2v[s], acc[ct], 0, 0, 0);
    }

    #pragma unroll
    for (int r = 0; r < 4; r++){
      const long orow = rbase + kg * 4 + r;
      if (orow >= M) continue;
      const long wrow = (long)operm[orow];
      #pragma unroll
      for (int ct = 0; ct < 8; ct++){
        const int c = ct * 16 + col0;
        Y[wrow * D + c] = (unsigned short)f2bf(acc[ct][r] + bs2[ct]);
      }
    }
  }
}

// ---------- fused residual block: Y = norm?(X) + silu(silu(norm?(X)@W1+b1)@W2+b2) ----------
template<bool NORM>
__global__ __launch_bounds__(256, 2) void k_res2(
    const float* __restrict__ X,
    const float* __restrict__ W1, const float* __restrict__ b1,
    const float* __restrict__ W2, const float* __restrict__ b2,
    const int* __restrict__ batch, const float* __restrict__ meanG,
    const float* __restrict__ rstdG, float* __restrict__ Y, int M)
{
  __shared__ short W1t[128 * 128];
  __shared__ short W2t[128 * 128];
  __shared__ short Ts[64 * 128];
  for (int i = threadIdx.x; i < 128 * 128; i += 256){
    int k = i >> 7, c = i & 127;
    W1t[c * 128 + k] = f2bf(W1[i]);
    W2t[c * 128 + k] = f2bf(W2[i]);
  }
  __syncthreads();

  const int lane = threadIdx.x & 63;
  const int wave = threadIdx.x >> 6;
  const int col0 = lane & 15;
  const int kg   = lane >> 4;

  bf16x8 B1f[8][4];
  #pragma unroll
  for (int ct = 0; ct < 8; ct++)
    #pragma unroll
    for (int s = 0; s < 4; s++)
      B1f[ct][s] = *(const bf16x8*)&W1t[(ct * 16 + col0) * 128 + s * 32 + kg * 8];

  float bs1[8], bs2[8];
  #pragma unroll
  for (int ct = 0; ct < 8; ct++){ bs1[ct] = b1[ct * 16 + col0]; bs2[ct] = b2[ct * 16 + col0]; }

  const long tiles = ((long)M + 63) >> 6;
  for (long t = blockIdx.x; t < tiles; t += gridDim.x){
    const long rbase = t * 64 + wave * 16;
    const long arow  = rbase + col0;
    const float* Xp = X + (arow < M ? arow : 0) * D;
    float xm = 0.f, xr = 1.f;
    if (NORM && arow < M){ int g = batch[arow]; xm = meanG[g]; xr = rstdG[g]; }

    bf16x8 Af[4];
    #pragma unroll
    for (int s = 0; s < 4; s++){
      const int kb = s * 32 + kg * 8;
      float4 lo = *(const float4*)(Xp + kb);
      float4 hi = *(const float4*)(Xp + kb + 4);
      bf16x8 a;
      a[0]=f2bf((lo.x-xm)*xr); a[1]=f2bf((lo.y-xm)*xr); a[2]=f2bf((lo.z-xm)*xr); a[3]=f2bf((lo.w-xm)*xr);
      a[4]=f2bf((hi.x-xm)*xr); a[5]=f2bf((hi.y-xm)*xr); a[6]=f2bf((hi.z-xm)*xr); a[7]=f2bf((hi.w-xm)*xr);
      Af[s] = a;
    }

    f32x4 acc[8];
    #pragma unroll
    for (int ct = 0; ct < 8; ct++){ acc[ct][0]=0.f; acc[ct][1]=0.f; acc[ct][2]=0.f; acc[ct][3]=0.f; }
    #pragma unroll
    for (int ct = 0; ct < 8; ct++)
      #pragma unroll
      for (int s = 0; s < 4; s++)
        acc[ct] = __builtin_amdgcn_mfma_f32_16x16x32_bf16(Af[s], B1f[ct][s], acc[ct], 0, 0, 0);

    #pragma unroll
    for (int ct = 0; ct < 8; ct++){
      const int c = ct * 16 + col0;
      #pragma unroll
      for (int r = 0; r < 4; r++){
        const int row = wave * 16 + kg * 4 + r;
        const int gg = (c >> 3) ^ (row & 7);
        Ts[row * 128 + gg * 8 + (c & 7)] = f2bf(siluf(acc[ct][r] + bs1[ct]));
      }
    }
    __syncthreads();

    const int row2 = wave * 16 + col0;
    bf16x8 A2f[4];
    #pragma unroll
    for (int s = 0; s < 4; s++){
      const int chunk = (s * 4 + kg) ^ (row2 & 7);
      A2f[s] = *(const bf16x8*)&Ts[row2 * 128 + chunk * 8];
    }
    __syncthreads();

    #pragma unroll
    for (int ct = 0; ct < 8; ct++){ acc[ct][0]=0.f; acc[ct][1]=0.f; acc[ct][2]=0.f; acc[ct][3]=0.f; }
    #pragma unroll
    for (int ct = 0; ct < 8; ct++){
      bf16x8 B2v[4];
      #pragma unroll
      for (int s = 0; s < 4; s++)
        B2v[s] = *(const bf16x8*)&W2t[(ct * 16 + col0) * 128 + s * 32 + kg * 8];
      #pragma unroll
      for (int s = 0; s < 4; s++)
        acc[ct] = __builtin_amdgcn_mfma_f32_16x16x32_bf16(A2f[s], B2v[s], acc[ct], 0, 0, 0);
    }

    #pragma unroll
    for (int r = 0; r < 4; r++){
      const long orow = rbase + kg * 4 + r;
      if (orow >= M) continue;
      float rm = 0.f, rr = 1.f;
      if (NORM){ int g = batch[orow]; rm = meanG[g]; rr = rstdG[g]; }
      #pragma unroll
      for (int ct = 0; ct < 8; ct++){
        const int c = ct * 16 + col0;
        float base = X[orow * D + c];
        if (NORM) base = (base - rm) * rr;
        Y[orow * D + c] = base + siluf(acc[ct][r] + bs2[ct]);
      }
    }
  }
}

// ---------- fused readout MLP: results[r] += silu(silu(X@W1+b1)@W2+b2) . w3 + b3 ----------
__global__ __launch_bounds__(256, 2) void k_read2(
    const float* __restrict__ X,
    const float* __restrict__ W1, const float* __restrict__ b1,
    const float* __restrict__ W2, const float* __restrict__ b2,
    const float* __restrict__ w3, const float* __restrict__ b3,
    float* __restrict__ results, int M)
{
  __shared__ short W1t[128 * 128];
  __shared__ short W2t[128 * 128];
  __shared__ short Ts[64 * 128];
  for (int i = threadIdx.x; i < 128 * 128; i += 256){
    int k = i >> 7, c = i & 127;
    W1t[c * 128 + k] = f2bf(W1[i]);
    W2t[c * 128 + k] = f2bf(W2[i]);
  }
  __syncthreads();

  const int lane = threadIdx.x & 63;
  const int wave = threadIdx.x >> 6;
  const int col0 = lane & 15;
  const int kg   = lane >> 4;

  bf16x8 B1f[8][4];
  #pragma unroll
  for (int ct = 0; ct < 8; ct++)
    #pragma unroll
    for (int s = 0; s < 4; s++)
      B1f[ct][s] = *(const bf16x8*)&W1t[(ct * 16 + col0) * 128 + s * 32 + kg * 8];

  float bs1[8], bs2[8], w3v[8];
  #pragma unroll
  for (int ct = 0; ct < 8; ct++){
    bs1[ct] = b1[ct * 16 + col0];
    bs2[ct] = b2[ct * 16 + col0];
    w3v[ct] = w3[ct * 16 + col0];
  }
  const float b3v = b3[0];

  const long tiles = ((long)M + 63) >> 6;
  for (long t = blockIdx.x; t < tiles; t += gridDim.x){
    const long rbase = t * 64 + wave * 16;
    const long arow  = rbase + col0;
    const float* Xp = X + (arow < M ? arow : 0) * D;

    bf16x8 Af[4];
    #pragma unroll
    for (int s = 0; s < 4; s++){
      const int kb = s * 32 + kg * 8;
      float4 lo = *(const float4*)(Xp + kb);
      float4 hi = *(const float4*)(Xp + kb + 4);
      bf16x8 a;
      a[0]=f2bf(lo.x); a[1]=f2bf(lo.y); a[2]=f2bf(lo.z); a[3]=f2bf(lo.w);
      a[4]=f2bf(hi.x); a[5]=f2bf(hi.y); a[6]=f2bf(hi.z); a[7]=f2bf(hi.w);
      Af[s] = a;
    }

    f32x4 acc[8];
    #pragma unroll
    for (int ct = 0; ct < 8; ct++){ acc[ct][0]=0.f; acc[ct][1]=0.f; acc[ct][2]=0.f; acc[ct][3]=0.f; }
    #pragma unroll
    for (int ct = 0; ct < 8; ct++)
      #pragma unroll
      for (int s = 0; s < 4; s++)
        acc[ct] = __builtin_amdgcn_mfma_f32_16x16x32_bf16(Af[s], B1f[ct][s], acc[ct], 0, 0, 0);

    #pragma unroll
    for (int ct = 0; ct < 8; ct++){
      const int c = ct * 16 + col0;
      #pragma unroll
      for (int r = 0; r < 4; r++){
        const int row = wave * 16 + kg * 4 + r;
        const int gg = (c >> 3) ^ (row & 7);
        Ts[row * 128 + gg * 8 + (c & 7)] = f2bf(siluf(acc[ct][r] + bs1[ct]));
      }
    }
    __syncthreads();

    const int row2 = wave * 16 + col0;
    bf16x8 A2f[4];
    #pragma unroll
    for (int s = 0; s < 4; s++){
      const int chunk = (s * 4 + kg) ^ (row2 & 7);
      A2f[s] = *(const bf16x8*)&Ts[row2 * 128 + chunk * 8];
    }
    __syncthreads();

    #pragma unroll
    for (int ct = 0; ct < 8; ct++){ acc[ct][0]=0.f; acc[ct][1]=0.f; acc[ct][2]=0.f; acc[ct][3]=0.f; }
    #pragma unroll
    for (int ct = 0; ct < 8; ct++){
      bf16x8 B2v[4];
      #pragma unroll
      for (int s = 0; s < 4; s++)
        B2v[s] = *(const bf16x8*)&W2t[(ct * 16 + col0) * 128 + s * 32 + kg * 8];
      #pragma unroll
      for (int s = 0; s < 4; s++)
        acc[ct] = __builtin_amdgcn_mfma_f32_16x16x32_bf16(A2f[s], B2v[s], acc[ct], 0, 0, 0);
    }

    #pragma unroll
    for (int r = 0; r < 4; r++){
      float vr = 0.f;
      #pragma unroll
      for (int ct = 0; ct < 8; ct++)
        vr += siluf(acc[ct][r] + bs2[ct]) * w3v[ct];
      #pragma unroll
      for (int off = 1; off < 16; off <<= 1) vr += __shfl_xor(vr, off, 64);
      const long orow = rbase + kg * 4 + r;
      if (col0 == 0 && orow < M) results[orow] += vr + b3v;
    }
  }
}

// ---------- CSR build ----------
__global__ void k_hist(const int* __restrict__ idx, int* __restrict__ cnt, int M)
{
  for (long i = (long)blockIdx.x * 256 + threadIdx.x; i < M; i += (long)gridDim.x * 256)
    atomicAdd(&cnt[idx[i]], 1);
}

__global__ void k_scan(const int* __restrict__ cnt, int* __restrict__ rowptr, int M)
{
  __shared__ int buf[1024];
  const int tid = threadIdx.x;
  const int PT = 16;
  int carry = 0;
  for (int base = 0; base < M; base += 1024 * PT){
    int loc[PT]; int s = 0;
    #pragma unroll
    for (int j = 0; j < PT; j++){
      int i = base + tid * PT + j;
      loc[j] = (i < M) ? cnt[i] : 0;
      s += loc[j];
    }
    buf[tid] = s; __syncthreads();
    for (int off = 1; off < 1024; off <<= 1){
      int t = (tid >= off) ? buf[tid - off] : 0;
      __syncthreads();
      buf[tid] += t;
      __syncthreads();
    }
    int run = buf[tid] - s + carry;
    carry += buf[1023];
    __syncthreads();
    #pragma unroll
    for (int j = 0; j < PT; j++){
      int i = base + tid * PT + j;
      if (i < M) rowptr[i] = run;
      run += loc[j];
    }
  }
  if (tid == 0) rowptr[M] = carry;
}

__global__ void k_fill(const int* __restrict__ idx, const int* __restrict__ rowptr,
                       int* __restrict__ cursor, int* __restrict__ ids, int M)
{
  for (long i = (long)blockIdx.x * 256 + threadIdx.x; i < M; i += (long)gridDim.x * 256){
    int sgm = idx[i];
    int pos = atomicAdd(&cursor[sgm], 1);
    ids[rowptr[sgm] + pos] = (int)i;
  }
}

// invD[eids[i]] = i; srcCSR[i] = srcA[eids[i]]; dstCSR[i] = dstA[eids[i]]
__global__ void k_invsrc(const int* __restrict__ eids, const int* __restrict__ srcA,
                         const int* __restrict__ dstA,
                         int* __restrict__ invD, int* __restrict__ srcCSR,
                         int* __restrict__ dstCSR, int E_)
{
  for (long i = (long)blockIdx.x * 256 + threadIdx.x; i < E_; i += (long)gridDim.x * 256){
    int e = eids[i];
    invD[e] = (int)i;
    srcCSR[i] = srcA[e];
    dstCSR[i] = dstA[e];
  }
}

// ---------- fp32 -> bf16 converter (setup) ----------
__global__ void k_cvt(const float* __restrict__ X, unsigned short* __restrict__ Y, long total4)
{
  for (long i = (long)blockIdx.x * 256 + threadIdx.x; i < total4; i += (long)gridDim.x * 256){
    float4 xv = *(const float4*)(X + i * 4);
    ushort4 o;
    o.x = (unsigned short)f2bf(xv.x); o.y = (unsigned short)f2bf(xv.y);
    o.z = (unsigned short)f2bf(xv.z); o.w = (unsigned short)f2bf(xv.w);
    *(ushort4*)(Y + i * 4) = o;
  }
}

// ---------- CSR gather-sum (atoms_rep) ----------
__global__ __launch_bounds__(256) void k_gather_sum(
    const float* __restrict__ X, const int* __restrict__ rowptr,
    const int* __restrict__ ids, float* __restrict__ Yat, int A_)
{
  const int lane = threadIdx.x & 63;
  const int wv   = threadIdx.x >> 6;
  for (long a = (long)blockIdx.x * 4 + wv; a < A_; a += (long)gridDim.x * 4){
    int beg = rowptr[a], end = rowptr[a + 1];
    float a0 = 0.f, a1 = 0.f;
    for (int i = beg; i < end; i++){
      const float* xp = X + (long)ids[i] * D;
      a0 += xp[lane]; a1 += xp[lane + 64];
    }
    Yat[a * D + lane] = a0; Yat[a * D + lane + 64] = a1;
  }
}

// ---------- CSR gather with rbf gate (readout scatter) ----------
__global__ __launch_bounds__(256) void k_gather_gate_sum(
    const float* __restrict__ X, const float* __restrict__ rbf,
    const float* __restrict__ Wr, const int* __restrict__ rowptr,
    const int* __restrict__ ids, float* __restrict__ Yat, int A_)
{
  __shared__ float Wrs[RBFD * D];
  for (int i = threadIdx.x; i < RBFD * D; i += 256) Wrs[i] = Wr[i];
  __syncthreads();
  const int lane = threadIdx.x & 63;
  const int wv   = threadIdx.x >> 6;
  for (long a = (long)blockIdx.x * 4 + wv; a < A_; a += (long)gridDim.x * 4){
    int beg = rowptr[a], end = rowptr[a + 1];
    float a0 = 0.f, a1 = 0.f;
    for (int i = beg; i < end; i++){
      long n = ids[i];
      const float* xp = X + n * D;
      const float* rb = rbf + n * RBFD;
      float g0 = 0.f, g1 = 0.f;
      #pragma unroll
      for (int r = 0; r < RBFD; r++){
        float rv = rb[r];
        g0 += rv * Wrs[r * D + lane];
        g1 += rv * Wrs[r * D + lane + 64];
      }
      a0 += xp[lane] * g0; a1 += xp[lane + 64] * g1;
    }
    Yat[a * D + lane] = a0; Yat[a * D + lane + 64] = a1;
  }
}

// ---------- edge-parallel pass A: w[e,h] = exp(q[dst].(k[src]+ek)/4); ve = (v[src]+ek)*sw ----------
// 16 lanes per edge, each lane owns 8 cols (16 B of bf16).
__global__ __launch_bounds__(256) void k_edge(
    const unsigned short* __restrict__ q, const unsigned short* __restrict__ k,
    const unsigned short* __restrict__ v, const unsigned short* __restrict__ ek,
    const unsigned short* __restrict__ sw,
    const int* __restrict__ srcCSR, const int* __restrict__ dstCSR,
    unsigned short* __restrict__ ve, float* __restrict__ w, int E_)
{
  const long tid = (long)blockIdx.x * 256 + threadIdx.x;
  const long i = tid >> 4;
  if (i >= E_) return;
  const int ll = (int)(threadIdx.x & 15);
  const int co = ll * 8;
  const long s = srcCSR[i], d = dstCSR[i];
  uint4 ekv = *(const uint4*)(ek + i * D + co);
  uint4 swv = *(const uint4*)(sw + i * D + co);
  uint4 kv  = *(const uint4*)(k + s * D + co);
  uint4 vv  = *(const uint4*)(v + s * D + co);
  uint4 qv  = *(const uint4*)(q + d * D + co);
  const unsigned* ep = (const unsigned*)&ekv;
  const unsigned* sp = (const unsigned*)&swv;
  const unsigned* kp = (const unsigned*)&kv;
  const unsigned* vp = (const unsigned*)&vv;
  const unsigned* qp = (const unsigned*)&qv;
  float t = 0.f;
  unsigned out[4];
  #pragma unroll
  for (int j = 0; j < 4; j++){
    float e0 = bflo(ep[j]), e1 = bfhi(ep[j]);
    t += bflo(qp[j]) * (bflo(kp[j]) + e0) + bfhi(qp[j]) * (bfhi(kp[j]) + e1);
    float u0 = (bflo(vp[j]) + e0) * bflo(sp[j]);
    float u1 = (bfhi(vp[j]) + e1) * bfhi(sp[j]);
    unsigned lo16 = (unsigned)(unsigned short)f2bf(u0);
    unsigned hi16 = (unsigned)(unsigned short)f2bf(u1);
    out[j] = lo16 | (hi16 << 16);
  }
  t += __shfl_xor(t, 1, 64);   // head = 16 cols = lane pair
  if ((ll & 1) == 0) w[i * NH + (ll >> 1)] = __expf(t * 0.25f);
  *(uint4*)(ve + i * D + co) = make_uint4(out[0], out[1], out[2], out[3]);
}

// ---------- pass B: h[d] = sum_e w*ve / sum_e w, + rbf gate + norm stats ----------
// wave per dst; lane owns col pair (2*lane, 2*lane+1); no shfl/exp/indirection in loop.
__global__ __launch_bounds__(256) void k_attn2(
    const unsigned short* __restrict__ ve, const float* __restrict__ w,
    const int* __restrict__ rowptr,
    const float* __restrict__ rbf, const float* __restrict__ Wr,
    const int* __restrict__ batch,
    double* __restrict__ sums, double* __restrict__ sumsq,
    float* __restrict__ h, int Nn)
{
  __shared__ float Wrs[RBFD * D];
  for (int i = threadIdx.x; i < RBFD * D; i += 256) Wrs[i] = Wr[i];
  __syncthreads();
  const int lane = threadIdx.x & 63;
  const int wv   = threadIdx.x >> 6;
  const int h8   = lane >> 3;     // head of cols (2*lane, 2*lane+1)
  for (long d = (long)blockIdx.x * 4 + wv; d < Nn; d += (long)gridDim.x * 4){
    const int beg = rowptr[d], end = rowptr[d + 1];
    float l = 0.f, a0 = 0.f, a1 = 0.f;
    for (int i = beg; i < end; i += 4){
      unsigned vv[4]; float ww[4];
      #pragma unroll
      for (int j = 0; j < 4; j++){
        const long idx = (i + j < end) ? (long)(i + j) : (long)(end - 1);
        vv[j] = *(const unsigned*)(ve + idx * D + 2 * lane);
        ww[j] = (i + j < end) ? w[idx * NH + h8] : 0.f;
      }
      #pragma unroll
      for (int j = 0; j < 4; j++){
        l  += ww[j];
        a0 += ww[j] * bflo(vv[j]);
        a1 += ww[j] * bfhi(vv[j]);
      }
    }
    const float inv = 1.f / (l + 1e-16f);
    a0 *= inv; a1 *= inv;
    // rbf gate
    const float* rb = rbf + d * RBFD;
    float g0 = 0.f, g1 = 0.f;
    #pragma unroll
    for (int r = 0; r < RBFD; r++){
      float rv = rb[r];
      g0 += rv * Wrs[r * D + 2 * lane];
      g1 += rv * Wrs[r * D + 2 * lane + 1];
    }
    a0 *= g0; a1 *= g1;
    *(float2*)(h + d * D + 2 * lane) = make_float2(a0, a1);
    // graph-norm stats
    float ss = a0 + a1, qq = a0 * a0 + a1 * a1;
    #pragma unroll
    for (int off = 1; off < 64; off <<= 1){
      ss += __shfl_xor(ss, off, 64);
      qq += __shfl_xor(qq, off, 64);
    }
    if (lane == 0){
      int g = batch[d];
      atomicAdd(&sums[g], (double)ss);
      atomicAdd(&sumsq[g], (double)qq);
    }
  }
}

// ---------- graph norm ----------
__global__ void k_count(const int* __restrict__ batch, int* __restrict__ cnt, int M)
{
  for (long i = (long)blockIdx.x * 256 + threadIdx.x; i < M; i += (long)gridDim.x * 256)
    atomicAdd(&cnt[batch[i]], 1);
}

__global__ void k_norm_final(const double* __restrict__ sums, const double* __restrict__ sumsq,
                             const int* __restrict__ cnt, float* __restrict__ meanG,
                             float* __restrict__ rstdG)
{
  int g = threadIdx.x;
  double c = (double)cnt[g] * (double)D;
  double mean = sums[g] / c;
  double var = sumsq[g] / c - mean * mean;
  meanG[g] = (float)mean;
  rstdG[g] = (float)(1.0 / sqrt(var + 1e-8));
}

__global__ void k_final(const float* __restrict__ results, const int* __restrict__ ab,
                        float* __restrict__ out, int A_)
{
  int i = blockIdx.x * 256 + threadIdx.x;
  if (i < A_) atomicAdd(&out[ab[i]], results[i] / 3.0f);
}

// ---------- fold w2@we, b2@we ----------
__global__ void k_w2e(const float* __restrict__ w2, const float* __restrict__ we,
                      float* __restrict__ W2e)
{
  int i = blockIdx.x >> 7;
  int r = blockIdx.x & 127;
  int c = threadIdx.x;
  const float* w2p = w2 + (size_t)i * D * D + (size_t)r * D;
  const float* wep = we + (size_t)i * D * D;
  float acc = 0.f;
  for (int j = 0; j < D; j++) acc += w2p[j] * wep[j * D + c];
  W2e[(size_t)i * D * D + (size_t)r * D + c] = acc;
}

__global__ void k_b2e(const float* __restrict__ b2, const float* __restrict__ we,
                      float* __restrict__ B2e)
{
  int i = blockIdx.x; int c = threadIdx.x;
  float acc = 0.f;
  for (int j = 0; j < D; j++) acc += b2[(size_t)i * D + j] * we[(size_t)i * D * D + j * D + c];
  B2e[(size_t)i * D + c] = acc;
}

extern "C" void kernel_launch(void* const* d_in, const int* in_sizes, int n_in,
                              void* d_out, int out_size, void* d_ws, size_t ws_size,
                              hipStream_t stream)
{
  const float* x          = (const float*)d_in[0];
  const float* node_rbf   = (const float*)d_in[1];
  const float* edge_sbf   = (const float*)d_in[2];
  const int*   edge_index = (const int*)d_in[3];
  const int*   pair_idx   = (const int*)d_in[4];
  const int*   eidx0      = (const int*)d_in[5];
  const int*   atom_batch = (const int*)d_in[6];
  const int*   batch      = (const int*)d_in[7];
  const float* edgenn_w1  = (const float*)d_in[8];
  const float* edgenn_b1  = (const float*)d_in[9];
  const float* edgenn_w2  = (const float*)d_in[10];
  const float* edgenn_b2  = (const float*)d_in[11];
  const float* conv_wq    = (const float*)d_in[12];
  const float* conv_wk    = (const float*)d_in[13];
  const float* conv_wv    = (const float*)d_in[14];
  const float* conv_we    = (const float*)d_in[15];
  const float* conv_wsbf  = (const float*)d_in[16];
  const float* conv_bsbf  = (const float*)d_in[17];
  const float* conv_wrbf  = (const float*)d_in[18];
  const float* dense_w    = (const float*)d_in[19];
  const float* dense_b    = (const float*)d_in[20];
  const float* bf_w       = (const float*)d_in[21];
  const float* bf_b       = (const float*)d_in[22];
  const float* af_w       = (const float*)d_in[23];
  const float* af_b       = (const float*)d_in[24];
  const float* read_wrbf  = (const float*)d_in[25];
  const float* read_w1    = (const float*)d_in[26];
  const float* read_b1    = (const float*)d_in[27];
  const float* read_w2    = (const float*)d_in[28];
  const float* read_b2    = (const float*)d_in[29];
  const float* read_w3    = (const float*)d_in[30];
  const float* read_b3    = (const float*)d_in[31];

  const int N = in_sizes[0] / D;
  const int E = in_sizes[4];
  const int A = in_sizes[6];
  const int G = out_size;

  char* p = (char*)d_ws;
  auto carve = [&](size_t bytes)->char*{ char* r = p; p += (bytes + 255) & ~(size_t)255; return r; };
  unsigned short* ekb  = (unsigned short*)carve((size_t)E * D * 2);  // ek bf16 (CSR)
  unsigned short* swb  = (unsigned short*)carve((size_t)E * D * 2);  // sw bf16 (CSR)
  unsigned short* veb  = (unsigned short*)carve((size_t)E * D * 2);  // ve bf16 (CSR)
  unsigned short* qb   = (unsigned short*)carve((size_t)N * D * 2);
  unsigned short* kb   = (unsigned short*)carve((size_t)N * D * 2);
  unsigned short* vb   = (unsigned short*)carve((size_t)N * D * 2);
  unsigned short* sbfb = (unsigned short*)carve((size_t)E * SBFD * 2);
  float*    wbuf    = (float*)carve((size_t)E * NH * 4);
  float*    hbuf    = (float*)carve((size_t)N * D * 4);
  float*    ping0   = (float*)carve((size_t)N * D * 4);
  float*    ping1   = (float*)carve((size_t)N * D * 4);
  float*    bufAtoms= (float*)carve((size_t)A * D * 4);
  float*    results = (float*)carve((size_t)A * 4);
  double*   sumG    = (double*)carve((size_t)G * 8);
  double*   sumsqG  = (double*)carve((size_t)G * 8);
  int*      cntG    = (int*)carve((size_t)G * 4);
  float*    meanG   = (float*)carve((size_t)G * 4);
  float*    rstdG   = (float*)carve((size_t)G * 4);
  float*    W2e     = (float*)carve((size_t)LAYERS * D * D * 4);
  float*    B2e     = (float*)carve((size_t)LAYERS * D * 4);
  int*      rowptrD = (int*)carve((size_t)(N + 1) * 4);
  int*      eidsD   = (int*)carve((size_t)E * 4);
  int*      invD    = (int*)carve((size_t)E * 4);
  int*      srcCSR  = (int*)carve((size_t)E * 4);
  int*      dstCSR  = (int*)carve((size_t)E * 4);
  int*      cntD    = (int*)carve((size_t)N * 4);
  int*      rowptrA = (int*)carve((size_t)(A + 1) * 4);
  int*      idsA    = (int*)carve((size_t)N * 4);
  int*      cntA    = (int*)carve((size_t)A * 4);

  const int* srcA = edge_index;
  const int* dstA = edge_index + E;

  auto ew_grid = [](long total){ long b = (total + 255) / 256; return (int)(b < 4096 ? b : 4096); };
  auto gemm_grid = [](int M){ long t = ((long)M + 63) / 64; return (int)(t < 1024 ? t : 1024); };
  const int gridAttn = (N + 3) / 4;
  const int gridAtom = (A + 3) / 4;
  const int gridEdge = (int)(((long)E * 16 + 255) / 256);

  // ---- one-time setup ----
  hipMemsetAsync(cntG, 0, (size_t)G * 4, stream);
  hipMemsetAsync(results, 0, (size_t)A * 4, stream);
  hipMemsetAsync(d_out, 0, (size_t)G * 4, stream);
  k_count<<<ew_grid(N), 256, 0, stream>>>(batch, cntG, N);
  k_w2e<<<LAYERS * D, D, 0, stream>>>(edgenn_w2, conv_we, W2e);
  k_b2e<<<LAYERS, D, 0, stream>>>(edgenn_b2, conv_we, B2e);
  k_cvt<<<4096, 256, 0, stream>>>(edge_sbf, sbfb, ((long)E * SBFD) / 4);
  // CSR by dst (edges)
  hipMemsetAsync(cntD, 0, (size_t)N * 4, stream);
  k_hist<<<ew_grid(E), 256, 0, stream>>>(dstA, cntD, E);
  k_scan<<<1, 1024, 0, stream>>>(cntD, rowptrD, N);
  hipMemsetAsync(cntD, 0, (size_t)N * 4, stream);
  k_fill<<<ew_grid(E), 256, 0, stream>>>(dstA, rowptrD, cntD, eidsD, E);
  k_invsrc<<<ew_grid(E), 256, 0, stream>>>(eidsD, srcA, dstA, invD, srcCSR, dstCSR, E);
  // CSR by atom (nodes)
  hipMemsetAsync(cntA, 0, (size_t)A * 4, stream);
  k_hist<<<ew_grid(N), 256, 0, stream>>>(eidx0, cntA, N);
  k_scan<<<1, 1024, 0, stream>>>(cntA, rowptrA, A);
  hipMemsetAsync(cntA, 0, (size_t)A * 4, stream);
  k_fill<<<ew_grid(N), 256, 0, stream>>>(eidx0, rowptrA, cntA, idsA, N);

  auto readout = [&](int i, const float* hb){
    k_gather_gate_sum<<<gridAtom, 256, 0, stream>>>(hb, node_rbf, read_wrbf + (size_t)i * RBFD * D,
                                                    rowptrA, idsA, bufAtoms, A);
    k_read2<<<gemm_grid(A), 256, 0, stream>>>(bufAtoms,
        read_w1 + (size_t)i*D*D, read_b1 + (size_t)i*D,
        read_w2 + (size_t)i*D*D, read_b2 + (size_t)i*D,
        read_w3 + (size_t)i*D, read_b3 + i, results, A);
  };

  readout(0, x);

  const float* cur = x;
  float* pp[2] = {ping0, ping1};
  for (int i = 0; i < LAYERS; i++){
    float* nxt = pp[i & 1];
    const size_t oDD = (size_t)i * D * D;
    // atoms_rep = segsum(cur, eidx0)  (CSR gather)
    k_gather_sum<<<gridAtom, 256, 0, stream>>>(cur, rowptrA, idsA, bufAtoms, A);
    // ek = silu(atoms_rep[pair_idx]@w1+b1) @ (w2@we) + b2@we  -> bf16, CSR order
    k_gemm2<<<gemm_grid(E),256,0,stream>>>(bufAtoms, pair_idx, edgenn_w1 + oDD, edgenn_b1 + (size_t)i*D,
                                           W2e + oDD, B2e + (size_t)i*D, ekb, invD, E);
    // q, k, v -> bf16
    k_gemm<D,0,false,false,false,false,true,false><<<gemm_grid(N),256,0,stream>>>(cur, nullptr, conv_wq + oDD, nullptr, nullptr, qb, nullptr, N);
    k_gemm<D,0,false,false,false,false,true,false><<<gemm_grid(N),256,0,stream>>>(cur, nullptr, conv_wk + oDD, nullptr, nullptr, kb, nullptr, N);
    k_gemm<D,0,false,false,false,false,true,false><<<gemm_grid(N),256,0,stream>>>(cur, nullptr, conv_wv + oDD, nullptr, nullptr, vb, nullptr, N);
    // sw = edge_sbf(bf16) @ wsbf + bsbf -> bf16, CSR order
    k_gemm<SBFD,0,false,true,false,true,true,true><<<gemm_grid(E),256,0,stream>>>(sbfb, nullptr, conv_wsbf + (size_t)i*SBFD*D, conv_bsbf + (size_t)i*D, nullptr, swb, invD, E);
    // pass A: edge-parallel weights + messages
    k_edge<<<gridEdge, 256, 0, stream>>>(qb, kb, vb, ekb, swb, srcCSR, dstCSR, veb, wbuf, E);
    // pass B: per-dst reduce + rbf gate + stats -> hbuf
    hipMemsetAsync(sumG, 0, (size_t)G * 16, stream);   // sumG + sumsqG (adjacent)
    k_attn2<<<gridAttn, 256, 0, stream>>>(veb, wbuf, rowptrD,
                                          node_rbf, conv_wrbf + (size_t)i*RBFD*D, batch,
                                          sumG, sumsqG, hbuf, N);
    k_norm_final<<<1, G, 0, stream>>>(sumG, sumsqG, cntG, meanG, rstdG);
    // bf residual block (absorbs norm-apply), in place on hbuf
    k_res2<true><<<gemm_grid(N),256,0,stream>>>(hbuf, bf_w + (size_t)i*2*D*D, bf_b + (size_t)i*2*D,
                                                bf_w + (size_t)i*2*D*D + D*D, bf_b + (size_t)i*2*D + D,
                                                batch, meanG, rstdG, hbuf, N);
    // dense + res0
    k_gemm<D,1,false,true,true,false,false,false><<<gemm_grid(N),256,0,stream>>>(hbuf, nullptr, dense_w + oDD, dense_b + (size_t)i*D, cur, nxt, nullptr, N);
    // af residual blocks, in place on nxt
    k_res2<false><<<gemm_grid(N),256,0,stream>>>(nxt, af_w + (size_t)i*4*D*D,         af_b + (size_t)i*4*D,
                                                 af_w + (size_t)i*4*D*D + D*D,       af_b + (size_t)i*4*D + D,
                                                 nullptr, nullptr, nullptr, nxt, N);
    k_res2<false><<<gemm_grid(N),256,0,stream>>>(nxt, af_w + (size_t)i*4*D*D + 2*D*D, af_b + (size_t)i*4*D + 2*D,
                                                 af_w + (size_t)i*4*D*D + 3*D*D,     af_b + (size_t)i*4*D + 3*D,
                                                 nullptr, nullptr, nullptr, nxt, N);
    // readout
    readout(i + 1, nxt);
    cur = nxt;
  }
  k_final<<<(A + 255) / 256, 256, 0, stream>>>(results, atom_batch, (float*)d_out, A);
}